// Round 1
// baseline (2082.573 us; speedup 1.0000x reference)
//
#include <hip/hip_runtime.h>
#include <math.h>

// Problem constants (fixed by reference)
constexpr int Bc = 2, Sc = 2048, Dc = 512, Hc = 8, DHc = 64;
constexpr int NQKV = 3 * Dc; // 1536

// ---------------------------------------------------------------------------
// GEMM: C[M,N] = A[M,K] @ Bm[N,K]^T + bias    (all fp32, row-major)
// MODE 0: write C row-major.  MODE 1: scatter into Q/K/V (H,B,S,DH) layout.
// Requires: BN/TN == 16, (BM/TM)*(BN/TN) == 256, BM*BK == 2048 (1 float4/thread)
// ---------------------------------------------------------------------------
template <int BM, int BN, int BK, int TM, int TN, int MODE>
__global__ __launch_bounds__(256) void gemm_abT(
    const float* __restrict__ A, const float* __restrict__ Bm,
    const float* __restrict__ bias, float* __restrict__ C,
    float* __restrict__ Qp, float* __restrict__ Kp, float* __restrict__ Vp,
    int M, int N, int Kd) {
  __shared__ float As[BK][BM];
  __shared__ float Bs[BK][BN];
  const int m0 = blockIdx.y * BM, n0 = blockIdx.x * BN;
  const int tid = threadIdx.x;
  const int tx = tid & 15;   // BN/TN == 16
  const int ty = tid >> 4;

  float acc[TM][TN];
#pragma unroll
  for (int i = 0; i < TM; ++i)
#pragma unroll
    for (int j = 0; j < TN; ++j) acc[i][j] = 0.f;

  for (int k0 = 0; k0 < Kd; k0 += BK) {
    // Stage A and B tiles: exactly one float4 per thread per tile.
    {
      const int row = tid / (BK / 4);
      const int kc4 = tid % (BK / 4);
      const float4 va =
          *(const float4*)(A + (size_t)(m0 + row) * Kd + k0 + kc4 * 4);
      As[kc4 * 4 + 0][row] = va.x;
      As[kc4 * 4 + 1][row] = va.y;
      As[kc4 * 4 + 2][row] = va.z;
      As[kc4 * 4 + 3][row] = va.w;
      const float4 vb =
          *(const float4*)(Bm + (size_t)(n0 + row) * Kd + k0 + kc4 * 4);
      Bs[kc4 * 4 + 0][row] = vb.x;
      Bs[kc4 * 4 + 1][row] = vb.y;
      Bs[kc4 * 4 + 2][row] = vb.z;
      Bs[kc4 * 4 + 3][row] = vb.w;
    }
    __syncthreads();
#pragma unroll
    for (int kk = 0; kk < BK; ++kk) {
      float a[TM], bb[TN];
#pragma unroll
      for (int i = 0; i < TM; ++i) a[i] = As[kk][ty * TM + i];
#pragma unroll
      for (int j = 0; j < TN; ++j) bb[j] = Bs[kk][tx * TN + j];
#pragma unroll
      for (int i = 0; i < TM; ++i)
#pragma unroll
        for (int j = 0; j < TN; ++j) acc[i][j] += a[i] * bb[j];
    }
    __syncthreads();
  }

// Epilogue
#pragma unroll
  for (int i = 0; i < TM; ++i) {
    const int r = m0 + ty * TM + i;
    const int batch = r / Sc;
    const int s = r - batch * Sc;
#pragma unroll
    for (int j = 0; j < TN; ++j) {
      const int c = n0 + tx * TN + j;
      const float val = acc[i][j] + bias[c];
      if (MODE == 0) {
        C[(size_t)r * N + c] = val;
      } else {
        // c -> (h, t3, dh) per reshape(B,S,H,3,DH)
        const int h = c / (3 * DHc);
        const int rem = c - h * 3 * DHc;
        const int t3 = rem / DHc;
        const int dh = rem - t3 * DHc;
        const size_t idx = (((size_t)h * Bc + batch) * Sc + s) * DHc + dh;
        float* dst = (t3 == 0) ? Qp : (t3 == 1) ? Kp : Vp;
        dst[idx] = val;
      }
    }
  }
}

// ---------------------------------------------------------------------------
// Attention: grid (S/4, B, H), block 256 = 4 waves; wave w owns q-row q0+w.
// logits = (q.k)/8 - exp2(-h)*shift; masked; softmax; o = p@V / sum.
// ---------------------------------------------------------------------------
constexpr int QPB = 4;

__global__ __launch_bounds__(256) void attn_kernel(
    const float* __restrict__ Q, const float* __restrict__ K,
    const float* __restrict__ V, const float* __restrict__ shift,
    const float* __restrict__ mask, float* __restrict__ O) {
  const int h = blockIdx.z, b = blockIdx.y;
  const int wave = threadIdx.x >> 6;
  const int lane = threadIdx.x & 63;
  const int q = blockIdx.x * QPB + wave;

  __shared__ float qs[QPB][DHc];
  __shared__ float Ks[64][DHc + 1];  // +1 pad: (lane+d)%32 -> 2-way only (free)
  __shared__ float p[QPB][Sc];

  const size_t hb = (size_t)h * Bc + b;
  const float* Kbase = K + hb * Sc * DHc;
  const float* Vbase = V + hb * Sc * DHc;
  qs[wave][lane] = Q[(hb * Sc + q) * DHc + lane];
  const float hs = exp2f(-(float)h);
  const float* sh = shift + ((size_t)b * Sc + q) * Sc;
  const float* mk = mask + ((size_t)b * Sc + q) * Sc;

  float mymax = -INFINITY;
  __syncthreads();

  for (int kt = 0; kt < Sc; kt += 64) {
    // Stage 64 K-rows (16 KB) cooperatively: 4 float4 per thread, coalesced.
#pragma unroll
    for (int j = 0; j < 4; ++j) {
      const int f = j * 256 + threadIdx.x;
      const int row = f >> 4, c4 = f & 15;
      const float4 v = ((const float4*)(Kbase + (size_t)kt * DHc))[f];
      float* dst = &Ks[row][c4 * 4];
      dst[0] = v.x;
      dst[1] = v.y;
      dst[2] = v.z;
      dst[3] = v.w;
    }
    __syncthreads();

    float acc = 0.f;
#pragma unroll
    for (int d = 0; d < DHc; ++d) acc += qs[wave][d] * Ks[lane][d];
    const int kidx = kt + lane;
    const float m = mk[kidx];
    float lg = acc * 0.125f - hs * sh[kidx];
    lg = lg * m - 1e8f * (1.f - m);
    p[wave][kidx] = lg;
    mymax = fmaxf(mymax, lg);
    __syncthreads();
  }

#pragma unroll
  for (int off = 32; off; off >>= 1)
    mymax = fmaxf(mymax, __shfl_xor(mymax, off, 64));

  float sum = 0.f;
  for (int k = lane; k < Sc; k += 64) {
    const float e = __expf(p[wave][k] - mymax);
    p[wave][k] = e;
    sum += e;
  }
#pragma unroll
  for (int off = 32; off; off >>= 1) sum += __shfl_xor(sum, off, 64);
  __syncthreads();

  // PV: lane = (key-phase kk4 in 0..3) x (d-quarter dq in 0..15); float4 V.
  const int kk4 = lane >> 4;
  const int dq = lane & 15;
  float4 o4 = {0.f, 0.f, 0.f, 0.f};
  for (int k = kk4; k < Sc; k += 4) {
    const float pw = p[wave][k];
    const float4 v = *(const float4*)(Vbase + (size_t)k * DHc + dq * 4);
    o4.x += pw * v.x;
    o4.y += pw * v.y;
    o4.z += pw * v.z;
    o4.w += pw * v.w;
  }
  // Combine the 4 key-phases (lanes differing in bits 4,5).
#pragma unroll
  for (int off = 16; off <= 32; off <<= 1) {
    o4.x += __shfl_xor(o4.x, off, 64);
    o4.y += __shfl_xor(o4.y, off, 64);
    o4.z += __shfl_xor(o4.z, off, 64);
    o4.w += __shfl_xor(o4.w, off, 64);
  }
  if (lane < 16) {
    const float inv = 1.f / sum;
    float4 r;
    r.x = o4.x * inv;
    r.y = o4.y * inv;
    r.z = o4.z * inv;
    r.w = o4.w * inv;
    // O layout (B,S,H,DH) so the out-proj sees contiguous (B*S, D).
    *(float4*)(O + (((size_t)b * Sc + q) * Hc + h) * DHc + dq * 4) = r;
  }
}

// ---------------------------------------------------------------------------
extern "C" void kernel_launch(void* const* d_in, const int* in_sizes, int n_in,
                              void* d_out, int out_size, void* d_ws,
                              size_t ws_size, hipStream_t stream) {
  const float* x = (const float*)d_in[0];
  const float* shift = (const float*)d_in[1];
  const float* mask = (const float*)d_in[2];
  const float* W = (const float*)d_in[3];
  const float* b = (const float*)d_in[4];
  const float* Wo = (const float*)d_in[5];
  const float* bo = (const float*)d_in[6];
  float* out = (float*)d_out;

  float* ws = (float*)d_ws;
  const size_t HBSD = (size_t)Hc * Bc * Sc * DHc;  // 2M floats
  float* Qp = ws;
  float* Kp = ws + HBSD;
  float* Vp = ws + 2 * HBSD;
  float* Op = ws + 3 * HBSD;

  // 1) QKV projection + scatter: M=4096, N=1536, K=512
  gemm_abT<128, 128, 8, 8, 8, 1>
      <<<dim3(NQKV / 128, (Bc * Sc) / 128), 256, 0, stream>>>(
          x, W, b, nullptr, Qp, Kp, Vp, Bc * Sc, NQKV, Dc);

  // 2) attention
  attn_kernel<<<dim3(Sc / QPB, Bc, Hc), 256, 0, stream>>>(Qp, Kp, Vp, shift,
                                                          mask, Op);

  // 3) output projection: M=4096, N=512, K=512
  gemm_abT<64, 64, 16, 4, 4, 0>
      <<<dim3(Dc / 64, (Bc * Sc) / 64), 256, 0, stream>>>(
          Op, Wo, bo, out, nullptr, nullptr, nullptr, Bc * Sc, Dc, Dc);
}

// Round 2
// 538.664 us; speedup vs baseline: 3.8662x; 3.8662x over previous
//
#include <hip/hip_runtime.h>
#include <math.h>

// Problem constants (fixed by reference)
constexpr int Bc = 2, Sc = 2048, Dc = 512, Hc = 8, DHc = 64;
constexpr int NQKV = 3 * Dc; // 1536

// ---------------------------------------------------------------------------
// GEMM: C[M,N] = A[M,K] @ Bm[N,K]^T + bias    (all fp32, row-major)
// MODE 0: write C row-major.  MODE 1: scatter into Q/K/V (H,B,S,DH) layout.
// Requires: BN/TN == 16, (BM/TM)*(BN/TN) == 256, BM*BK == 2048 (1 float4/thread)
// ---------------------------------------------------------------------------
template <int BM, int BN, int BK, int TM, int TN, int MODE>
__global__ __launch_bounds__(256) void gemm_abT(
    const float* __restrict__ A, const float* __restrict__ Bm,
    const float* __restrict__ bias, float* __restrict__ C,
    float* __restrict__ Qp, float* __restrict__ Kp, float* __restrict__ Vp,
    int M, int N, int Kd) {
  __shared__ float As[BK][BM];
  __shared__ float Bs[BK][BN];
  const int m0 = blockIdx.y * BM, n0 = blockIdx.x * BN;
  const int tid = threadIdx.x;
  const int tx = tid & 15;   // BN/TN == 16
  const int ty = tid >> 4;

  float acc[TM][TN];
#pragma unroll
  for (int i = 0; i < TM; ++i)
#pragma unroll
    for (int j = 0; j < TN; ++j) acc[i][j] = 0.f;

  for (int k0 = 0; k0 < Kd; k0 += BK) {
    {
      const int row = tid / (BK / 4);
      const int kc4 = tid % (BK / 4);
      const float4 va =
          *(const float4*)(A + (size_t)(m0 + row) * Kd + k0 + kc4 * 4);
      As[kc4 * 4 + 0][row] = va.x;
      As[kc4 * 4 + 1][row] = va.y;
      As[kc4 * 4 + 2][row] = va.z;
      As[kc4 * 4 + 3][row] = va.w;
      const float4 vb =
          *(const float4*)(Bm + (size_t)(n0 + row) * Kd + k0 + kc4 * 4);
      Bs[kc4 * 4 + 0][row] = vb.x;
      Bs[kc4 * 4 + 1][row] = vb.y;
      Bs[kc4 * 4 + 2][row] = vb.z;
      Bs[kc4 * 4 + 3][row] = vb.w;
    }
    __syncthreads();
#pragma unroll
    for (int kk = 0; kk < BK; ++kk) {
      float a[TM], bb[TN];
#pragma unroll
      for (int i = 0; i < TM; ++i) a[i] = As[kk][ty * TM + i];
#pragma unroll
      for (int j = 0; j < TN; ++j) bb[j] = Bs[kk][tx * TN + j];
#pragma unroll
      for (int i = 0; i < TM; ++i)
#pragma unroll
        for (int j = 0; j < TN; ++j) acc[i][j] += a[i] * bb[j];
    }
    __syncthreads();
  }

#pragma unroll
  for (int i = 0; i < TM; ++i) {
    const int r = m0 + ty * TM + i;
    const int batch = r / Sc;
    const int s = r - batch * Sc;
#pragma unroll
    for (int j = 0; j < TN; ++j) {
      const int c = n0 + tx * TN + j;
      const float val = acc[i][j] + bias[c];
      if (MODE == 0) {
        C[(size_t)r * N + c] = val;
      } else {
        const int h = c / (3 * DHc);
        const int rem = c - h * 3 * DHc;
        const int t3 = rem / DHc;
        const int dh = rem - t3 * DHc;
        const size_t idx = (((size_t)h * Bc + batch) * Sc + s) * DHc + dh;
        float* dst = (t3 == 0) ? Qp : (t3 == 1) ? Kp : Vp;
        dst[idx] = val;
      }
    }
  }
}

// ---------------------------------------------------------------------------
// Flash-style attention: block = 64 queries for one (h,b). 256 thr = 16x16
// thread grid, 4x4 register tile. Key-tiles of 64. Online softmax.
// LDS: Qs^T [d][q], KV buffer (K as [d][k], then V as [k][d]), Ps [k][q].
// ---------------------------------------------------------------------------
constexpr int BQ = 64;

__global__ __launch_bounds__(256) void attn_kernel(
    const float* __restrict__ Q, const float* __restrict__ K,
    const float* __restrict__ V, const float* __restrict__ shift,
    const float* __restrict__ mask, float* __restrict__ O) {
  const int h = blockIdx.z, b = blockIdx.y;
  const int q0 = blockIdx.x * BQ;
  const int tid = threadIdx.x;
  const int tx = tid & 15, ty = tid >> 4;

  __shared__ float Qs[64][68];   // [d][q]
  __shared__ float KVs[64][68];  // K phase: [d][k]; V phase: [k][d]
  __shared__ float Ps[64][68];   // [k][q]

  const size_t hb = (size_t)h * Bc + b;
  const float* Kb = K + hb * Sc * DHc;
  const float* Vb = V + hb * Sc * DHc;
  const float hs = exp2f(-(float)h);

  // Stage Q tile transposed: [d][q]
#pragma unroll
  for (int j = 0; j < 4; ++j) {
    const int f = j * 256 + tid;
    const int r = f >> 4, c4 = f & 15;
    const float4 v =
        *(const float4*)(Q + (hb * Sc + q0 + r) * (size_t)DHc + c4 * 4);
    Qs[c4 * 4 + 0][r] = v.x;
    Qs[c4 * 4 + 1][r] = v.y;
    Qs[c4 * 4 + 2][r] = v.z;
    Qs[c4 * 4 + 3][r] = v.w;
  }

  float m_i[4], l_i[4], o[4][4];
#pragma unroll
  for (int i = 0; i < 4; ++i) {
    m_i[i] = -INFINITY;
    l_i[i] = 0.f;
#pragma unroll
    for (int j = 0; j < 4; ++j) o[i][j] = 0.f;
  }

  const size_t shBase = ((size_t)b * Sc + q0 + ty * 4) * Sc + tx * 4;
  __syncthreads();

  for (int kt = 0; kt < Sc; kt += 64) {
    // ---- stage K tile transposed [d][k]
#pragma unroll
    for (int j = 0; j < 4; ++j) {
      const int f = j * 256 + tid;
      const int r = f >> 4, c4 = f & 15;
      const float4 v =
          *(const float4*)(Kb + (size_t)(kt + r) * DHc + c4 * 4);
      KVs[c4 * 4 + 0][r] = v.x;
      KVs[c4 * 4 + 1][r] = v.y;
      KVs[c4 * 4 + 2][r] = v.z;
      KVs[c4 * 4 + 3][r] = v.w;
    }
    __syncthreads();

    // ---- S = Q @ K^T (64x64x64), 4x4 per thread
    float acc[4][4];
#pragma unroll
    for (int i = 0; i < 4; ++i)
#pragma unroll
      for (int j = 0; j < 4; ++j) acc[i][j] = 0.f;
#pragma unroll 4
    for (int kk = 0; kk < 64; ++kk) {
      const float4 a4 = *(const float4*)&Qs[kk][ty * 4];
      const float4 b4 = *(const float4*)&KVs[kk][tx * 4];
      const float av[4] = {a4.x, a4.y, a4.z, a4.w};
      const float bv[4] = {b4.x, b4.y, b4.z, b4.w};
#pragma unroll
      for (int i = 0; i < 4; ++i)
#pragma unroll
        for (int j = 0; j < 4; ++j) acc[i][j] += av[i] * bv[j];
    }

    // ---- logits: scale, shift, mask
#pragma unroll
    for (int i = 0; i < 4; ++i) {
      const size_t off = shBase + (size_t)i * Sc + kt;
      const float4 s4 = *(const float4*)(shift + off);
      const float4 m4 = *(const float4*)(mask + off);
      const float sv[4] = {s4.x, s4.y, s4.z, s4.w};
      const float mv[4] = {m4.x, m4.y, m4.z, m4.w};
#pragma unroll
      for (int j = 0; j < 4; ++j) {
        float lg = acc[i][j] * 0.125f - hs * sv[j];
        acc[i][j] = lg * mv[j] - 1e8f * (1.f - mv[j]);
      }
    }

    // ---- online softmax update (reduce over the 16 tx lanes)
#pragma unroll
    for (int i = 0; i < 4; ++i) {
      float rmax = fmaxf(fmaxf(acc[i][0], acc[i][1]),
                         fmaxf(acc[i][2], acc[i][3]));
#pragma unroll
      for (int off = 1; off <= 8; off <<= 1)
        rmax = fmaxf(rmax, __shfl_xor(rmax, off, 64));
      const float mnew = fmaxf(m_i[i], rmax);
      const float alpha = __expf(m_i[i] - mnew);
      float rs = 0.f;
#pragma unroll
      for (int j = 0; j < 4; ++j) {
        const float p = __expf(acc[i][j] - mnew);
        acc[i][j] = p;
        rs += p;
      }
#pragma unroll
      for (int off = 1; off <= 8; off <<= 1) rs += __shfl_xor(rs, off, 64);
      l_i[i] = l_i[i] * alpha + rs;
      m_i[i] = mnew;
#pragma unroll
      for (int j = 0; j < 4; ++j) o[i][j] *= alpha;
    }

    // ---- write P to LDS as [k][q]
#pragma unroll
    for (int i = 0; i < 4; ++i)
#pragma unroll
      for (int j = 0; j < 4; ++j) Ps[tx * 4 + j][ty * 4 + i] = acc[i][j];
    __syncthreads();  // Ps written; K reads done

    // ---- stage V tile natural [k][d]
#pragma unroll
    for (int j = 0; j < 4; ++j) {
      const int f = j * 256 + tid;
      const int r = f >> 4, c4 = f & 15;
      const float4 v =
          *(const float4*)(Vb + (size_t)(kt + r) * DHc + c4 * 4);
      *(float4*)&KVs[r][c4 * 4] = v;
    }
    __syncthreads();

    // ---- O += P @ V (64x64x64)
#pragma unroll 4
    for (int kk = 0; kk < 64; ++kk) {
      const float4 a4 = *(const float4*)&Ps[kk][ty * 4];
      const float4 v4 = *(const float4*)&KVs[kk][tx * 4];
      const float av[4] = {a4.x, a4.y, a4.z, a4.w};
      const float vv[4] = {v4.x, v4.y, v4.z, v4.w};
#pragma unroll
      for (int i = 0; i < 4; ++i)
#pragma unroll
        for (int j = 0; j < 4; ++j) o[i][j] += av[i] * vv[j];
    }
    __syncthreads();  // done with Ps/KVs before next overwrite
  }

  // ---- epilogue: O layout (B,S,H,DH)
#pragma unroll
  for (int i = 0; i < 4; ++i) {
    const float inv = 1.f / l_i[i];
    float4 r;
    r.x = o[i][0] * inv;
    r.y = o[i][1] * inv;
    r.z = o[i][2] * inv;
    r.w = o[i][3] * inv;
    const int q = q0 + ty * 4 + i;
    *(float4*)(O + (((size_t)b * Sc + q) * Hc + h) * DHc + tx * 4) = r;
  }
}

// ---------------------------------------------------------------------------
extern "C" void kernel_launch(void* const* d_in, const int* in_sizes, int n_in,
                              void* d_out, int out_size, void* d_ws,
                              size_t ws_size, hipStream_t stream) {
  const float* x = (const float*)d_in[0];
  const float* shift = (const float*)d_in[1];
  const float* mask = (const float*)d_in[2];
  const float* W = (const float*)d_in[3];
  const float* b = (const float*)d_in[4];
  const float* Wo = (const float*)d_in[5];
  const float* bo = (const float*)d_in[6];
  float* out = (float*)d_out;

  float* ws = (float*)d_ws;
  const size_t HBSD = (size_t)Hc * Bc * Sc * DHc;  // 2M floats
  float* Qp = ws;
  float* Kp = ws + HBSD;
  float* Vp = ws + 2 * HBSD;
  float* Op = ws + 3 * HBSD;

  // 1) QKV projection + scatter: M=4096, N=1536, K=512
  gemm_abT<128, 128, 8, 8, 8, 1>
      <<<dim3(NQKV / 128, (Bc * Sc) / 128), 256, 0, stream>>>(
          x, W, b, nullptr, Qp, Kp, Vp, Bc * Sc, NQKV, Dc);

  // 2) attention (flash-style tiled)
  attn_kernel<<<dim3(Sc / BQ, Bc, Hc), 256, 0, stream>>>(Qp, Kp, Vp, shift,
                                                         mask, Op);

  // 3) output projection: M=4096, N=512, K=512
  gemm_abT<64, 64, 16, 4, 4, 0>
      <<<dim3(Dc / 64, (Bc * Sc) / 64), 256, 0, stream>>>(
          Op, Wo, bo, out, nullptr, nullptr, nullptr, Bc * Sc, Dc, Dc);
}

// Round 3
// 394.532 us; speedup vs baseline: 5.2786x; 1.3653x over previous
//
#include <hip/hip_runtime.h>
#include <math.h>

// Problem constants (fixed by reference)
constexpr int Bc = 2, Sc = 2048, Dc = 512, Hc = 8, DHc = 64;
constexpr int NQKV = 3 * Dc;  // 1536

typedef __attribute__((ext_vector_type(8))) __bf16 bf16x8;
typedef __attribute__((ext_vector_type(16))) float f32x16;

__device__ inline unsigned short f2bf(float f) {  // fp32 -> bf16 RNE
  unsigned u = __float_as_uint(f);
  return (unsigned short)((u + 0x7FFFu + ((u >> 16) & 1u)) >> 16);
}
__device__ inline float bf2f(unsigned short h) {
  return __uint_as_float(((unsigned)h) << 16);
}

// ---------------------------------------------------------------------------
// GEMM1: qkv = x @ W^T + b, epilogue splits to bf16 hi/lo planes:
//   Q,K: [h][b][s][dh] natural;  V: [h][b][dh][s] TRANSPOSED (for PV A-frags).
// BM=128,BN=128,BK=8,TM=8,TN=8.
// ---------------------------------------------------------------------------
template <int BM, int BN, int BK, int TM, int TN>
__global__ __launch_bounds__(256) void gemm_qkv(
    const float* __restrict__ A, const float* __restrict__ Bm,
    const float* __restrict__ bias, unsigned short* __restrict__ Qhi,
    unsigned short* __restrict__ Qlo, unsigned short* __restrict__ Khi,
    unsigned short* __restrict__ Klo, unsigned short* __restrict__ Vthi,
    unsigned short* __restrict__ Vtlo, int M, int N, int Kd) {
  __shared__ float As[BK][BM];
  __shared__ float Bs[BK][BN];
  const int m0 = blockIdx.y * BM, n0 = blockIdx.x * BN;
  const int tid = threadIdx.x;
  const int tx = tid & 15, ty = tid >> 4;

  float acc[TM][TN];
#pragma unroll
  for (int i = 0; i < TM; ++i)
#pragma unroll
    for (int j = 0; j < TN; ++j) acc[i][j] = 0.f;

  for (int k0 = 0; k0 < Kd; k0 += BK) {
    {
      const int row = tid / (BK / 4);
      const int kc4 = tid % (BK / 4);
      const float4 va =
          *(const float4*)(A + (size_t)(m0 + row) * Kd + k0 + kc4 * 4);
      As[kc4 * 4 + 0][row] = va.x;
      As[kc4 * 4 + 1][row] = va.y;
      As[kc4 * 4 + 2][row] = va.z;
      As[kc4 * 4 + 3][row] = va.w;
      const float4 vb =
          *(const float4*)(Bm + (size_t)(n0 + row) * Kd + k0 + kc4 * 4);
      Bs[kc4 * 4 + 0][row] = vb.x;
      Bs[kc4 * 4 + 1][row] = vb.y;
      Bs[kc4 * 4 + 2][row] = vb.z;
      Bs[kc4 * 4 + 3][row] = vb.w;
    }
    __syncthreads();
#pragma unroll
    for (int kk = 0; kk < BK; ++kk) {
      float a[TM], bb[TN];
#pragma unroll
      for (int i = 0; i < TM; ++i) a[i] = As[kk][ty * TM + i];
#pragma unroll
      for (int j = 0; j < TN; ++j) bb[j] = Bs[kk][tx * TN + j];
#pragma unroll
      for (int i = 0; i < TM; ++i)
#pragma unroll
        for (int j = 0; j < TN; ++j) acc[i][j] += a[i] * bb[j];
    }
    __syncthreads();
  }

#pragma unroll
  for (int i = 0; i < TM; ++i) {
    const int r = m0 + ty * TM + i;
    const int batch = r / Sc;
    const int s = r - batch * Sc;
#pragma unroll
    for (int j = 0; j < TN; ++j) {
      const int c = n0 + tx * TN + j;
      const float val = acc[i][j] + bias[c];
      const int h = c / (3 * DHc);
      const int rem = c - h * 3 * DHc;
      const int t3 = rem / DHc;
      const int dh = rem - t3 * DHc;
      const unsigned short hi = f2bf(val);
      const unsigned short lo = f2bf(val - bf2f(hi));
      const size_t hbq = (size_t)h * Bc + batch;
      if (t3 == 2) {
        const size_t idx = (hbq * DHc + dh) * Sc + s;  // transposed
        Vthi[idx] = hi;
        Vtlo[idx] = lo;
      } else {
        const size_t idx = (hbq * Sc + s) * DHc + dh;
        if (t3 == 0) {
          Qhi[idx] = hi;
          Qlo[idx] = lo;
        } else {
          Khi[idx] = hi;
          Klo[idx] = lo;
        }
      }
    }
  }
}

// ---------------------------------------------------------------------------
// MFMA flash attention. Block = 256 thr = 4 waves = (wq 0..1) x (wk 0..1).
// Wave (wq,wk): q rows [q0+32wq, +32), keys kt = it*64 + wk*32 per iter.
// S^T = K·Q^T via 32x32x16 bf16 MFMA (split hi/lo, 3 terms).
// Softmax per-lane (q = C-layout column). P -> LDS bf16 hi/lo -> PV.
// O^T accumulated (M=dh), written coalesced to Ot[d_global][token].
// wk pair merged at end (flash-decoding style).
// ---------------------------------------------------------------------------
__global__ __launch_bounds__(256, 2) void attn_mfma(
    const unsigned short* __restrict__ Qhi, const unsigned short* __restrict__ Qlo,
    const unsigned short* __restrict__ Khi, const unsigned short* __restrict__ Klo,
    const unsigned short* __restrict__ Vthi, const unsigned short* __restrict__ Vtlo,
    const float* __restrict__ shift, const float* __restrict__ mask,
    float* __restrict__ Ot) {
  const int h = blockIdx.z, b = blockIdx.y;
  const int q0 = blockIdx.x * 64;
  const int wave = threadIdx.x >> 6;
  const int wq = wave >> 1, wk = wave & 1;
  const int lane = threadIdx.x & 63;
  const int l31 = lane & 31, lhi = lane >> 5;

  __shared__ __align__(16) unsigned short Ks[2][2][32][72];  // [pl][wk][key][dh+pad]
  __shared__ __align__(16) unsigned short Vs[2][2][64][40];  // [pl][wk][dh][key+pad]
  __shared__ __align__(16) char Pregion[20480];  // P planes; merge bufs at end
  unsigned short* Phi = (unsigned short*)Pregion;        // [4][32][40]
  unsigned short* Plo = Phi + 4 * 32 * 40;

  const size_t hb = (size_t)h * Bc + b;
  const int qg = q0 + wq * 32 + l31;

  // Preload Q B-frags (n=q=l31, k=dh): 4 ksteps x {hi,lo}
  bf16x8 qf[2][4];
  {
    const size_t qbase = (hb * Sc + qg) * DHc;
#pragma unroll
    for (int t = 0; t < 4; ++t) {
      qf[0][t] = *(const bf16x8*)(Qhi + qbase + t * 16 + lhi * 8);
      qf[1][t] = *(const bf16x8*)(Qlo + qbase + t * 16 + lhi * 8);
    }
  }
  const float hs = exp2f(-(float)h);
  const float* shrow = shift + ((size_t)b * Sc + qg) * Sc;
  const float* mkrow = mask + ((size_t)b * Sc + qg) * Sc;

  float m_run = -INFINITY, l_run = 0.f;
  f32x16 o0, o1;
#pragma unroll
  for (int i = 0; i < 16; ++i) {
    o0[i] = 0.f;
    o1[i] = 0.f;
  }

  unsigned short* PhiW = Phi + (wave * 32 + l31) * 40;
  unsigned short* PloW = Plo + (wave * 32 + l31) * 40;
  const unsigned short* PhiR = Phi + wave * 32 * 40 + l31 * 40;
  const unsigned short* PloR = Plo + wave * 32 * 40 + l31 * 40;

  for (int it = 0; it < 32; ++it) {
    const int kt = it * 64 + wk * 32;
    // ---- stage: wq=0 stages K[wk] (32 keys x 64 dh), wq=1 stages Vt[wk]
    if (wq == 0) {
      const int r = lane >> 1, h2 = lane & 1;
      const size_t gb = (hb * Sc + kt + r) * DHc + h2 * 32;
#pragma unroll
      for (int c = 0; c < 4; ++c)
        *(uint4*)&Ks[0][wk][r][h2 * 32 + c * 8] = *(const uint4*)(Khi + gb + c * 8);
#pragma unroll
      for (int c = 0; c < 4; ++c)
        *(uint4*)&Ks[1][wk][r][h2 * 32 + c * 8] = *(const uint4*)(Klo + gb + c * 8);
    } else {
      const size_t gb = (hb * DHc + lane) * Sc + kt;  // lane = dh row
#pragma unroll
      for (int c = 0; c < 4; ++c)
        *(uint4*)&Vs[0][wk][lane][c * 8] = *(const uint4*)(Vthi + gb + c * 8);
#pragma unroll
      for (int c = 0; c < 4; ++c)
        *(uint4*)&Vs[1][wk][lane][c * 8] = *(const uint4*)(Vtlo + gb + c * 8);
    }
    __syncthreads();

    // ---- S^T = K·Q^T (m=key, n=q), split: Khi*Qhi + Khi*Qlo + Klo*Qhi
    f32x16 s;
#pragma unroll
    for (int i = 0; i < 16; ++i) s[i] = 0.f;
#pragma unroll
    for (int t = 0; t < 4; ++t) {
      const bf16x8 khi = *(const bf16x8*)&Ks[0][wk][l31][t * 16 + lhi * 8];
      const bf16x8 klo = *(const bf16x8*)&Ks[1][wk][l31][t * 16 + lhi * 8];
      s = __builtin_amdgcn_mfma_f32_32x32x16_bf16(khi, qf[0][t], s, 0, 0, 0);
      s = __builtin_amdgcn_mfma_f32_32x32x16_bf16(khi, qf[1][t], s, 0, 0, 0);
      s = __builtin_amdgcn_mfma_f32_32x32x16_bf16(klo, qf[0][t], s, 0, 0, 0);
    }

    // ---- logits + online softmax (q = lane column; keys = 16 regs)
    float p[16];
    float kmax = -INFINITY;
#pragma unroll
    for (int c = 0; c < 4; ++c) {
      const int ko = kt + c * 8 + lhi * 4;  // key of reg 4c (+0..3)
      const float4 s4 = *(const float4*)(shrow + ko);
      const float4 m4 = *(const float4*)(mkrow + ko);
      const float sv[4] = {s4.x, s4.y, s4.z, s4.w};
      const float mv[4] = {m4.x, m4.y, m4.z, m4.w};
#pragma unroll
      for (int e = 0; e < 4; ++e) {
        float lg = s[4 * c + e] * 0.125f - hs * sv[e];
        lg = lg * mv[e] - 1e8f * (1.f - mv[e]);
        p[4 * c + e] = lg;
        kmax = fmaxf(kmax, lg);
      }
    }
    kmax = fmaxf(kmax, __shfl_xor(kmax, 32, 64));
    const float mnew = fmaxf(m_run, kmax);
    const float alpha = __expf(m_run - mnew);
    float rsum = 0.f;
#pragma unroll
    for (int r = 0; r < 16; ++r) {
      p[r] = __expf(p[r] - mnew);
      rsum += p[r];
    }
    rsum += __shfl_xor(rsum, 32, 64);
    l_run = l_run * alpha + rsum;
    m_run = mnew;
#pragma unroll
    for (int i = 0; i < 16; ++i) {
      o0[i] *= alpha;
      o1[i] *= alpha;
    }

    // ---- write P hi/lo to LDS [q][key] (wave-private; packed b64)
#pragma unroll
    for (int c = 0; c < 4; ++c) {
      const int ko = c * 8 + lhi * 4;
      unsigned short hbits[4], lbits[4];
#pragma unroll
      for (int e = 0; e < 4; ++e) {
        const float ph = p[4 * c + e];
        hbits[e] = f2bf(ph);
        lbits[e] = f2bf(ph - bf2f(hbits[e]));
      }
      uint2 whi, wlo;
      whi.x = (unsigned)hbits[0] | ((unsigned)hbits[1] << 16);
      whi.y = (unsigned)hbits[2] | ((unsigned)hbits[3] << 16);
      wlo.x = (unsigned)lbits[0] | ((unsigned)lbits[1] << 16);
      wlo.y = (unsigned)lbits[2] | ((unsigned)lbits[3] << 16);
      *(uint2*)&PhiW[ko] = whi;
      *(uint2*)&PloW[ko] = wlo;
    }

    // ---- O^T += V^T·P^T  (A: m=dh from Vs; B: n=q from P)
#pragma unroll
    for (int t = 0; t < 2; ++t) {
      const bf16x8 pfh = *(const bf16x8*)&PhiR[t * 16 + lhi * 8];
      const bf16x8 pfl = *(const bf16x8*)&PloR[t * 16 + lhi * 8];
      {
        const bf16x8 vhi = *(const bf16x8*)&Vs[0][wk][l31][t * 16 + lhi * 8];
        const bf16x8 vlo = *(const bf16x8*)&Vs[1][wk][l31][t * 16 + lhi * 8];
        o0 = __builtin_amdgcn_mfma_f32_32x32x16_bf16(vhi, pfh, o0, 0, 0, 0);
        o0 = __builtin_amdgcn_mfma_f32_32x32x16_bf16(vhi, pfl, o0, 0, 0, 0);
        o0 = __builtin_amdgcn_mfma_f32_32x32x16_bf16(vlo, pfh, o0, 0, 0, 0);
      }
      {
        const bf16x8 vhi = *(const bf16x8*)&Vs[0][wk][32 + l31][t * 16 + lhi * 8];
        const bf16x8 vlo = *(const bf16x8*)&Vs[1][wk][32 + l31][t * 16 + lhi * 8];
        o1 = __builtin_amdgcn_mfma_f32_32x32x16_bf16(vhi, pfh, o1, 0, 0, 0);
        o1 = __builtin_amdgcn_mfma_f32_32x32x16_bf16(vhi, pfl, o1, 0, 0, 0);
        o1 = __builtin_amdgcn_mfma_f32_32x32x16_bf16(vlo, pfh, o1, 0, 0, 0);
      }
    }
    __syncthreads();
  }

  // ---- merge wk=0 / wk=1 (same wq) through LDS (aliases P region)
  float* mL = (float*)Pregion;  // [2][32]
  float* lL = mL + 64;          // [2][32]
  float* Om = lL + 64;          // [2][64][33]
  if (wk == 1) {
    if (lhi == 0) {
      mL[wq * 32 + l31] = m_run;
      lL[wq * 32 + l31] = l_run;
    }
#pragma unroll
    for (int mt = 0; mt < 2; ++mt)
#pragma unroll
      for (int r = 0; r < 16; ++r) {
        const int row = mt * 32 + (r & 3) + 8 * (r >> 2) + 4 * lhi;
        Om[(wq * 64 + row) * 33 + l31] = (mt ? o1[r] : o0[r]);
      }
  }
  __syncthreads();
  if (wk == 0) {
    const float m1 = mL[wq * 32 + l31];
    const float l1v = lL[wq * 32 + l31];
    const float mst = fmaxf(m_run, m1);
    const float a0 = __expf(m_run - mst), a1 = __expf(m1 - mst);
    const float inv = 1.f / (a0 * l_run + a1 * l1v);
    const size_t tok = (size_t)b * Sc + qg;
#pragma unroll
    for (int mt = 0; mt < 2; ++mt)
#pragma unroll
      for (int r = 0; r < 16; ++r) {
        const int row = mt * 32 + (r & 3) + 8 * (r >> 2) + 4 * lhi;
        const float val =
            (a0 * (mt ? o1[r] : o0[r]) + a1 * Om[(wq * 64 + row) * 33 + l31]) * inv;
        Ot[(size_t)(h * DHc + row) * (Bc * Sc) + tok] = val;
      }
  }
}

// ---------------------------------------------------------------------------
// GEMM2: out[M,N] = Ot^T @ Wo^T + bo, with Ot stored [Kd][M] (column-major A).
// BM=64,BN=64,BK=16,TM=4,TN=4.
// ---------------------------------------------------------------------------
__global__ __launch_bounds__(256) void gemm_oT(
    const float* __restrict__ At, const float* __restrict__ Bm,
    const float* __restrict__ bias, float* __restrict__ C, int M, int N,
    int Kd) {
  __shared__ float As[16][64];
  __shared__ float Bs[16][64];
  const int m0 = blockIdx.y * 64, n0 = blockIdx.x * 64;
  const int tid = threadIdx.x;
  const int tx = tid & 15, ty = tid >> 4;

  float acc[4][4];
#pragma unroll
  for (int i = 0; i < 4; ++i)
#pragma unroll
    for (int j = 0; j < 4; ++j) acc[i][j] = 0.f;

  for (int k0 = 0; k0 < Kd; k0 += 16) {
    {
      const int k = tid >> 4, m4 = tid & 15;
      *(float4*)&As[k][m4 * 4] =
          *(const float4*)(At + (size_t)(k0 + k) * M + m0 + m4 * 4);
      const int row = tid >> 2, kc4 = tid & 3;
      const float4 vb =
          *(const float4*)(Bm + (size_t)(n0 + row) * Kd + k0 + kc4 * 4);
      Bs[kc4 * 4 + 0][row] = vb.x;
      Bs[kc4 * 4 + 1][row] = vb.y;
      Bs[kc4 * 4 + 2][row] = vb.z;
      Bs[kc4 * 4 + 3][row] = vb.w;
    }
    __syncthreads();
#pragma unroll
    for (int kk = 0; kk < 16; ++kk) {
      float a[4], bb[4];
#pragma unroll
      for (int i = 0; i < 4; ++i) a[i] = As[kk][ty * 4 + i];
#pragma unroll
      for (int j = 0; j < 4; ++j) bb[j] = Bs[kk][tx * 4 + j];
#pragma unroll
      for (int i = 0; i < 4; ++i)
#pragma unroll
        for (int j = 0; j < 4; ++j) acc[i][j] += a[i] * bb[j];
    }
    __syncthreads();
  }

#pragma unroll
  for (int i = 0; i < 4; ++i) {
    const int r = m0 + ty * 4 + i;
#pragma unroll
    for (int j = 0; j < 4; ++j) {
      const int c = n0 + tx * 4 + j;
      C[(size_t)r * N + c] = acc[i][j] + bias[c];
    }
  }
}

// ---------------------------------------------------------------------------
extern "C" void kernel_launch(void* const* d_in, const int* in_sizes, int n_in,
                              void* d_out, int out_size, void* d_ws,
                              size_t ws_size, hipStream_t stream) {
  const float* x = (const float*)d_in[0];
  const float* shift = (const float*)d_in[1];
  const float* mask = (const float*)d_in[2];
  const float* W = (const float*)d_in[3];
  const float* b = (const float*)d_in[4];
  const float* Wo = (const float*)d_in[5];
  const float* bo = (const float*)d_in[6];
  float* out = (float*)d_out;

  // Workspace layout (32 MiB total):
  // 6 bf16 planes (4 MiB each): Qhi Qlo Khi Klo Vthi Vtlo ; then Ot fp32 8 MiB
  const size_t PLANE = (size_t)Hc * Bc * Sc * DHc;  // 2,097,152 elements
  unsigned short* Qhi = (unsigned short*)d_ws;
  unsigned short* Qlo = Qhi + PLANE;
  unsigned short* Khi = Qlo + PLANE;
  unsigned short* Klo = Khi + PLANE;
  unsigned short* Vthi = Klo + PLANE;
  unsigned short* Vtlo = Vthi + PLANE;
  float* Ot = (float*)(Vtlo + PLANE);  // [Dc][Bc*Sc]

  // 1) QKV projection -> split bf16 planes (V transposed)
  gemm_qkv<128, 128, 8, 8, 8>
      <<<dim3(NQKV / 128, (Bc * Sc) / 128), 256, 0, stream>>>(
          x, W, b, Qhi, Qlo, Khi, Klo, Vthi, Vtlo, Bc * Sc, NQKV, Dc);

  // 2) MFMA flash attention -> Ot [Dc][Bc*Sc]
  attn_mfma<<<dim3(Sc / 64, Bc, Hc), 256, 0, stream>>>(
      Qhi, Qlo, Khi, Klo, Vthi, Vtlo, shift, mask, Ot);

  // 3) output projection from transposed Ot
  gemm_oT<<<dim3(Dc / 64, (Bc * Sc) / 64), 256, 0, stream>>>(
      Ot, Wo, bo, out, Bc * Sc, Dc, Dc);
}

// Round 4
// 338.270 us; speedup vs baseline: 6.1565x; 1.1663x over previous
//
#include <hip/hip_runtime.h>
#include <math.h>

// Problem constants (fixed by reference)
constexpr int Bc = 2, Sc = 2048, Dc = 512, Hc = 8, DHc = 64;
constexpr int NQKV = 3 * Dc;  // 1536

typedef unsigned short u16;
typedef unsigned int u32;
typedef __attribute__((ext_vector_type(8))) __bf16 bf16x8;
typedef __attribute__((ext_vector_type(16))) float f32x16;

#define MFMA32 __builtin_amdgcn_mfma_f32_32x32x16_bf16

// Truncation hi/lo split of two floats, packed: ret.x = (hi(b)<<16)|hi(a),
// ret.y = lo-pair. hi = truncate-to-bf16; lo = bf16(residual). hi+lo keeps
// ~16-17 mantissa bits (fp32-level for our purposes).
__device__ inline uint2 splitpack2(float a, float b) {
  u32 ua = __float_as_uint(a), ub = __float_as_uint(b);
  u32 hi = (ub & 0xFFFF0000u) | (ua >> 16);
  float ra = a - __uint_as_float(ua & 0xFFFF0000u);
  float rb = b - __uint_as_float(ub & 0xFFFF0000u);
  u32 lo = (__float_as_uint(rb) & 0xFFFF0000u) | (__float_as_uint(ra) >> 16);
  return uint2{hi, lo};
}
__device__ inline void split1(float v, u16& hi, u16& lo) {
  u32 u = __float_as_uint(v);
  hi = (u16)(u >> 16);
  float r = v - __uint_as_float(u & 0xFFFF0000u);
  lo = (u16)(__float_as_uint(r) >> 16);
}

// ---------------------------------------------------------------------------
// Split x (4096x512) and W (1536x512) fp32 -> bf16 hi/lo planes (row-major).
// ---------------------------------------------------------------------------
constexpr int NX4 = (4096 * 512) / 4;  // 524288 float4s
constexpr int NW4 = (1536 * 512) / 4;  // 196608

__global__ __launch_bounds__(256) void split_inputs(
    const float* __restrict__ x, const float* __restrict__ W,
    u16* __restrict__ xhi, u16* __restrict__ xlo, u16* __restrict__ whi,
    u16* __restrict__ wlo) {
  const int f = blockIdx.x * 256 + threadIdx.x;
  const float* src;
  u16 *dh_, *dl_;
  int idx;
  if (f < NX4) {
    src = x; dh_ = xhi; dl_ = xlo; idx = f;
  } else {
    src = W; dh_ = whi; dl_ = wlo; idx = f - NX4;
  }
  const float4 v = ((const float4*)src)[idx];
  const uint2 p0 = splitpack2(v.x, v.y), p1 = splitpack2(v.z, v.w);
  ((uint2*)dh_)[idx] = uint2{p0.x, p1.x};
  ((uint2*)dl_)[idx] = uint2{p0.y, p1.y};
}

// ---------------------------------------------------------------------------
// GEMM1 (MFMA): qkv = x @ W^T + b. Tiles 128x64, BK=32, 4 waves (2x2), each
// wave 2 m-tiles of 32x32. LDS in fragment-major layout [p][mt][t][lane][8].
// Epilogue splits to Q/K [h][b][s][dh] and V^T [h][b][dh][s] bf16 planes.
// ---------------------------------------------------------------------------
__global__ __launch_bounds__(256, 2) void gemm1_mfma(
    const u16* __restrict__ xhi, const u16* __restrict__ xlo,
    const u16* __restrict__ whi, const u16* __restrict__ wlo,
    const float* __restrict__ bias, u16* __restrict__ Qhi,
    u16* __restrict__ Qlo, u16* __restrict__ Khi, u16* __restrict__ Klo,
    u16* __restrict__ Vthi, u16* __restrict__ Vtlo) {
  __shared__ __align__(16) u16 Af[2][4][2][64][8];  // 16 KB
  __shared__ __align__(16) u16 Bf[2][2][2][64][8];  // 8 KB
  const int tid = threadIdx.x;
  const int wave = tid >> 6, lane = tid & 63, l31 = lane & 31, lhi = lane >> 5;
  const int wm = wave >> 1, wn = wave & 1;
  const int m0 = blockIdx.y * 128, n0 = blockIdx.x * 64;

  f32x16 acc[2];
#pragma unroll
  for (int r = 0; r < 16; ++r) {
    acc[0][r] = 0.f;
    acc[1][r] = 0.f;
  }

  for (int k0 = 0; k0 < 512; k0 += 32) {
    // stage A: 1024 16B chunks (2 planes x 128 m x 4 kc)
#pragma unroll
    for (int i = 0; i < 4; ++i) {
      const int f = i * 256 + tid;
      const int p = f >> 9, rem = f & 511, m = rem >> 2, c = rem & 3;
      const u16* src = (p ? xlo : xhi) + (size_t)(m0 + m) * 512 + k0 + c * 8;
      *(uint4*)&Af[p][m >> 5][c >> 1][(c & 1) * 32 + (m & 31)][0] =
          *(const uint4*)src;
    }
    // stage B: 512 chunks
#pragma unroll
    for (int i = 0; i < 2; ++i) {
      const int f = i * 256 + tid;
      const int p = f >> 8, rem = f & 255, n = rem >> 2, c = rem & 3;
      const u16* src = (p ? wlo : whi) + (size_t)(n0 + n) * 512 + k0 + c * 8;
      *(uint4*)&Bf[p][n >> 5][c >> 1][(c & 1) * 32 + (n & 31)][0] =
          *(const uint4*)src;
    }
    __syncthreads();
#pragma unroll
    for (int t = 0; t < 2; ++t) {
      const bf16x8 bh = *(const bf16x8*)&Bf[0][wn][t][lane][0];
      const bf16x8 bl = *(const bf16x8*)&Bf[1][wn][t][lane][0];
#pragma unroll
      for (int ti = 0; ti < 2; ++ti) {
        const bf16x8 ah = *(const bf16x8*)&Af[0][wm * 2 + ti][t][lane][0];
        const bf16x8 al = *(const bf16x8*)&Af[1][wm * 2 + ti][t][lane][0];
        acc[ti] = MFMA32(ah, bh, acc[ti], 0, 0, 0);
        acc[ti] = MFMA32(ah, bl, acc[ti], 0, 0, 0);
        acc[ti] = MFMA32(al, bh, acc[ti], 0, 0, 0);
      }
    }
    __syncthreads();
  }

  // epilogue: C col (lane&31) = n, rows per reg. t3 uniform per wave.
  const int n = n0 + wn * 32 + l31;
  const float bn = bias[n];
  const int h = n / 192, rem = n - h * 192, t3 = rem >> 6, dh = rem & 63;
#pragma unroll
  for (int ti = 0; ti < 2; ++ti)
#pragma unroll
    for (int r = 0; r < 16; ++r) {
      const int m = m0 + wm * 64 + ti * 32 + (r & 3) + 8 * (r >> 2) + 4 * lhi;
      const int batch = m >> 11, s = m & 2047;
      const float val = acc[ti][r] + bn;
      u16 hi, lo;
      split1(val, hi, lo);
      const int hbq = h * 2 + batch;
      if (t3 == 2) {
        const size_t idx = ((size_t)hbq * 64 + dh) * 2048 + s;
        Vthi[idx] = hi;
        Vtlo[idx] = lo;
      } else {
        const size_t idx = ((size_t)hbq * 2048 + s) * 64 + dh;
        if (t3 == 0) {
          Qhi[idx] = hi;
          Qlo[idx] = lo;
        } else {
          Khi[idx] = hi;
          Klo[idx] = lo;
        }
      }
    }
}

// ---------------------------------------------------------------------------
// MFMA flash attention, fragment-major LDS (conflict-free b128 everywhere).
// Block = 4 waves = (wq 0..1) x (wk 0..1); 64 q-rows per block.
// Output: Otc chunk layout, element (d, tok) at ((d>>3)*4096 + tok)*8 + (d&7),
// bf16 hi/lo planes.
// ---------------------------------------------------------------------------
__global__ __launch_bounds__(256, 3) void attn_mfma(
    const u16* __restrict__ Qhi, const u16* __restrict__ Qlo,
    const u16* __restrict__ Khi, const u16* __restrict__ Klo,
    const u16* __restrict__ Vthi, const u16* __restrict__ Vtlo,
    const float* __restrict__ shift, const float* __restrict__ mask,
    u16* __restrict__ Othi, u16* __restrict__ Otlo) {
  const int h = blockIdx.z, b = blockIdx.y;
  const int q0 = blockIdx.x * 64;
  const int wave = threadIdx.x >> 6;
  const int wq = wave >> 1, wk = wave & 1;
  const int lane = threadIdx.x & 63;
  const int l31 = lane & 31, lhi = lane >> 5;

  // 48 KB pool:
  //  Kf [pl2][wk2][t4][64][8]       @ 0      (8192 u16)
  //  Vf [pl2][wk2][mt2][t2][64][8]  @ 8192   (8192 u16)
  //  Pf [pl2][wave4][t2][64][8]     @ 16384  (8192 u16)
  //  merge region (fp32) aliases offset 0 after the K-loop.
  __shared__ __align__(16) u16 smem[24576];
  u16* Kf = smem;
  u16* Vf = smem + 8192;
  u16* Pf = smem + 16384;

  const size_t hb = (size_t)h * Bc + b;
  const int qg = q0 + wq * 32 + l31;

  // Q B-frags from global: n=q (l31), k = t*16 + lhi*8 + j
  bf16x8 qf[2][4];
  {
    const size_t qbase = (hb * Sc + qg) * DHc;
#pragma unroll
    for (int t = 0; t < 4; ++t) {
      qf[0][t] = *(const bf16x8*)(Qhi + qbase + t * 16 + lhi * 8);
      qf[1][t] = *(const bf16x8*)(Qlo + qbase + t * 16 + lhi * 8);
    }
  }
  const float hs = exp2f(-(float)h);
  const float* shrow = shift + ((size_t)b * Sc + qg) * Sc;
  const float* mkrow = mask + ((size_t)b * Sc + qg) * Sc;

  float m_run = -INFINITY, l_run = 0.f;
  f32x16 o0, o1;
#pragma unroll
  for (int i = 0; i < 16; ++i) {
    o0[i] = 0.f;
    o1[i] = 0.f;
  }

  for (int it = 0; it < 32; ++it) {
    const int kt = it * 64 + wk * 32;
    // ---- staging: wq=0 waves stage K[wk]; wq=1 waves stage V^T[wk]
    if (wq == 0) {
      const int r = lane >> 1, half = lane & 1;
      const size_t gb = (hb * Sc + kt + r) * 64 + half * 32;
#pragma unroll
      for (int c = 0; c < 4; ++c) {
        const int dhc = half * 32 + c * 8;
        const int t = dhc >> 4, lh = (dhc >> 3) & 1;
        *(uint4*)&Kf[(((0 * 2 + wk) * 4 + t) * 64 + lh * 32 + r) * 8] =
            *(const uint4*)(Khi + gb + c * 8);
        *(uint4*)&Kf[(((1 * 2 + wk) * 4 + t) * 64 + lh * 32 + r) * 8] =
            *(const uint4*)(Klo + gb + c * 8);
      }
    } else {
      const size_t gb = (hb * 64 + lane) * 2048 + kt;  // lane = dh
      const int mt = lane >> 5, dl = lane & 31;
#pragma unroll
      for (int c = 0; c < 4; ++c) {
        const int t = c >> 1, lh = c & 1;
        *(uint4*)&Vf[((((0 * 2 + wk) * 2 + mt) * 2 + t) * 64 + lh * 32 + dl) * 8] =
            *(const uint4*)(Vthi + gb + c * 8);
        *(uint4*)&Vf[((((1 * 2 + wk) * 2 + mt) * 2 + t) * 64 + lh * 32 + dl) * 8] =
            *(const uint4*)(Vtlo + gb + c * 8);
      }
    }
    __syncthreads();

    // ---- S^T = K·Q^T (m=key, n=q): Khi*Qhi + Khi*Qlo + Klo*Qhi
    f32x16 s;
#pragma unroll
    for (int i = 0; i < 16; ++i) s[i] = 0.f;
#pragma unroll
    for (int t = 0; t < 4; ++t) {
      const bf16x8 kh = *(const bf16x8*)&Kf[(((0 * 2 + wk) * 4 + t) * 64 + lane) * 8];
      const bf16x8 kl = *(const bf16x8*)&Kf[(((1 * 2 + wk) * 4 + t) * 64 + lane) * 8];
      s = MFMA32(kh, qf[0][t], s, 0, 0, 0);
      s = MFMA32(kh, qf[1][t], s, 0, 0, 0);
      s = MFMA32(kl, qf[0][t], s, 0, 0, 0);
    }

    // ---- logits + online softmax (q = lane col; key = kt + 8c + 4lhi + e)
    float p[16];
    float kmax = -INFINITY;
#pragma unroll
    for (int c = 0; c < 4; ++c) {
      const int ko = kt + c * 8 + lhi * 4;
      const float4 s4 = *(const float4*)(shrow + ko);
      const float4 m4 = *(const float4*)(mkrow + ko);
      const float sv[4] = {s4.x, s4.y, s4.z, s4.w};
      const float mv[4] = {m4.x, m4.y, m4.z, m4.w};
#pragma unroll
      for (int e = 0; e < 4; ++e) {
        float lg = s[4 * c + e] * 0.125f - hs * sv[e];
        lg = lg * mv[e] - 1e8f * (1.f - mv[e]);
        p[4 * c + e] = lg;
        kmax = fmaxf(kmax, lg);
      }
    }
    kmax = fmaxf(kmax, __shfl_xor(kmax, 32, 64));
    const float mnew = fmaxf(m_run, kmax);
    const float alpha = __expf(m_run - mnew);
    float rsum = 0.f;
#pragma unroll
    for (int r = 0; r < 16; ++r) {
      p[r] = __expf(p[r] - mnew);
      rsum += p[r];
    }
    rsum += __shfl_xor(rsum, 32, 64);
    l_run = l_run * alpha + rsum;
    m_run = mnew;
#pragma unroll
    for (int i = 0; i < 16; ++i) {
      o0[i] *= alpha;
      o1[i] *= alpha;
    }

    // ---- P -> Pf (wave-private), frag layout: elem (q=l31, kl=c*8+lhi*4+e)
#pragma unroll
    for (int c = 0; c < 4; ++c) {
      const uint2 s01 = splitpack2(p[4 * c + 0], p[4 * c + 1]);
      const uint2 s23 = splitpack2(p[4 * c + 2], p[4 * c + 3]);
      const int t = c >> 1, lh = c & 1;
      const int bi = ((wave * 2 + t) * 64 + lh * 32 + l31) * 8 + lhi * 4;
      *(uint2*)&Pf[bi] = uint2{s01.x, s23.x};
      *(uint2*)&Pf[4096 + bi] = uint2{s01.y, s23.y};
    }

    // ---- O^T += V^T · P^T
#pragma unroll
    for (int t = 0; t < 2; ++t) {
      const bf16x8 ph = *(const bf16x8*)&Pf[((wave * 2 + t) * 64 + lane) * 8];
      const bf16x8 pl_ = *(const bf16x8*)&Pf[4096 + ((wave * 2 + t) * 64 + lane) * 8];
      bf16x8 vh = *(const bf16x8*)&Vf[((((0 * 2 + wk) * 2 + 0) * 2 + t) * 64 + lane) * 8];
      bf16x8 vl = *(const bf16x8*)&Vf[((((1 * 2 + wk) * 2 + 0) * 2 + t) * 64 + lane) * 8];
      o0 = MFMA32(vh, ph, o0, 0, 0, 0);
      o0 = MFMA32(vh, pl_, o0, 0, 0, 0);
      o0 = MFMA32(vl, ph, o0, 0, 0, 0);
      vh = *(const bf16x8*)&Vf[((((0 * 2 + wk) * 2 + 1) * 2 + t) * 64 + lane) * 8];
      vl = *(const bf16x8*)&Vf[((((1 * 2 + wk) * 2 + 1) * 2 + t) * 64 + lane) * 8];
      o1 = MFMA32(vh, ph, o1, 0, 0, 0);
      o1 = MFMA32(vh, pl_, o1, 0, 0, 0);
      o1 = MFMA32(vl, ph, o1, 0, 0, 0);
    }
    __syncthreads();
  }

  // ---- merge wk=0/1 (same wq) through LDS (aliases pool; safe post-barrier)
  float* mL = (float*)smem;  // [64]
  float* lL = mL + 64;       // [64]
  float* Om = lL + 64;       // [2][64][33]
  if (wk == 1) {
    if (lhi == 0) {
      mL[wq * 32 + l31] = m_run;
      lL[wq * 32 + l31] = l_run;
    }
#pragma unroll
    for (int mt = 0; mt < 2; ++mt)
#pragma unroll
      for (int r = 0; r < 16; ++r) {
        const int row = mt * 32 + (r & 3) + 8 * (r >> 2) + 4 * lhi;
        Om[(wq * 64 + row) * 33 + l31] = (mt ? o1[r] : o0[r]);
      }
  }
  __syncthreads();
  if (wk == 0) {
    const float m1 = mL[wq * 32 + l31];
    const float l1v = lL[wq * 32 + l31];
    const float mst = fmaxf(m_run, m1);
    const float a0 = __expf(m_run - mst), a1 = __expf(m1 - mst);
    const float inv = 1.f / (a0 * l_run + a1 * l1v);
    const int tok = b * 2048 + qg;
#pragma unroll
    for (int mt = 0; mt < 2; ++mt)
#pragma unroll
      for (int r = 0; r < 16; ++r) {
        const int row = mt * 32 + (r & 3) + 8 * (r >> 2) + 4 * lhi;
        const float val =
            (a0 * (mt ? o1[r] : o0[r]) + a1 * Om[(wq * 64 + row) * 33 + l31]) *
            inv;
        const int d = h * 64 + row;
        u16 hi, lo;
        split1(val, hi, lo);
        const size_t idx = ((size_t)(d >> 3) * 4096 + tok) * 8 + (d & 7);
        Othi[idx] = hi;
        Otlo[idx] = lo;
      }
  }
}

// ---------------------------------------------------------------------------
// GEMM2 (MFMA): out = o @ Wo^T + bo. A from Otc chunk planes (b128 staging),
// B = Wo fp32 converted inline. Tiles 64x64, BK=32, 4 waves (2x2), 1 tile ea.
// ---------------------------------------------------------------------------
__global__ __launch_bounds__(256, 2) void gemm2_mfma(
    const u16* __restrict__ Othi, const u16* __restrict__ Otlo,
    const float* __restrict__ Wo, const float* __restrict__ bo,
    float* __restrict__ out) {
  __shared__ __align__(16) u16 Af[2][2][2][64][8];  // 8 KB
  __shared__ __align__(16) u16 Bf[2][2][2][64][8];  // 8 KB
  const int tid = threadIdx.x;
  const int wave = tid >> 6, lane = tid & 63, l31 = lane & 31, lhi = lane >> 5;
  const int wm = wave >> 1, wn = wave & 1;
  const int m0 = blockIdx.y * 64, n0 = blockIdx.x * 64;

  f32x16 acc;
#pragma unroll
  for (int r = 0; r < 16; ++r) acc[r] = 0.f;

  for (int k0 = 0; k0 < 512; k0 += 32) {
    // A: 512 chunks from Otc layout ((kglob>>3)*4096 + token)*8 + (kglob&7)
#pragma unroll
    for (int i = 0; i < 2; ++i) {
      const int f = i * 256 + tid;
      const int p = f >> 8, rem = f & 255, c = rem >> 6, tok = rem & 63;
      const u16* src =
          (p ? Otlo : Othi) + ((size_t)(k0 / 8 + c) * 4096 + m0 + tok) * 8;
      *(uint4*)&Af[p][tok >> 5][c >> 1][(c & 1) * 32 + (tok & 31)][0] =
          *(const uint4*)src;
    }
    // B: Wo fp32 rows, inline truncation split
    {
      const int n = tid >> 2, c = tid & 3;
      const float* src = Wo + (size_t)(n0 + n) * 512 + k0 + c * 8;
      const float4 v0 = *(const float4*)src;
      const float4 v1 = *(const float4*)(src + 4);
      const uint2 q0 = splitpack2(v0.x, v0.y), q1 = splitpack2(v0.z, v0.w);
      const uint2 q2 = splitpack2(v1.x, v1.y), q3 = splitpack2(v1.z, v1.w);
      const uint4 hi4 = {q0.x, q1.x, q2.x, q3.x};
      const uint4 lo4 = {q0.y, q1.y, q2.y, q3.y};
      *(uint4*)&Bf[0][n >> 5][c >> 1][(c & 1) * 32 + (n & 31)][0] = hi4;
      *(uint4*)&Bf[1][n >> 5][c >> 1][(c & 1) * 32 + (n & 31)][0] = lo4;
    }
    __syncthreads();
#pragma unroll
    for (int t = 0; t < 2; ++t) {
      const bf16x8 ah = *(const bf16x8*)&Af[0][wm][t][lane][0];
      const bf16x8 al = *(const bf16x8*)&Af[1][wm][t][lane][0];
      const bf16x8 bh = *(const bf16x8*)&Bf[0][wn][t][lane][0];
      const bf16x8 bl = *(const bf16x8*)&Bf[1][wn][t][lane][0];
      acc = MFMA32(ah, bh, acc, 0, 0, 0);
      acc = MFMA32(ah, bl, acc, 0, 0, 0);
      acc = MFMA32(al, bh, acc, 0, 0, 0);
    }
    __syncthreads();
  }

  const int n = n0 + wn * 32 + l31;
  const float bn = bo[n];
#pragma unroll
  for (int r = 0; r < 16; ++r) {
    const int m = m0 + wm * 32 + (r & 3) + 8 * (r >> 2) + 4 * lhi;
    out[(size_t)m * 512 + n] = acc[r] + bn;
  }
}

// ---------------------------------------------------------------------------
extern "C" void kernel_launch(void* const* d_in, const int* in_sizes, int n_in,
                              void* d_out, int out_size, void* d_ws,
                              size_t ws_size, hipStream_t stream) {
  const float* x = (const float*)d_in[0];
  const float* shift = (const float*)d_in[1];
  const float* mask = (const float*)d_in[2];
  const float* W = (const float*)d_in[3];
  const float* b = (const float*)d_in[4];
  const float* Wo = (const float*)d_in[5];
  const float* bo = (const float*)d_in[6];
  float* out = (float*)d_out;

  // ws (32 MiB): [0,6P): Q/K/V hi+lo planes. [6P,8P): phase-1 W planes,
  // later overwritten by Ot planes (W dead after gemm1).
  // d_out (8 MiB) doubles as x hi/lo planes until gemm2 writes the output.
  const size_t P = (size_t)Hc * Bc * Sc * DHc;  // 2,097,152
  u16* ws0 = (u16*)d_ws;
  u16* Qhi = ws0;
  u16* Qlo = ws0 + P;
  u16* Khi = ws0 + 2 * P;
  u16* Klo = ws0 + 3 * P;
  u16* Vthi = ws0 + 4 * P;
  u16* Vtlo = ws0 + 5 * P;
  u16* Whi = ws0 + 6 * P;
  u16* Wlo = Whi + (size_t)NQKV * Dc;  // 786,432 elements
  u16* Othi = ws0 + 6 * P;             // aliases dead W planes
  u16* Otlo = ws0 + 7 * P;
  u16* xhi = (u16*)d_out;
  u16* xlo = xhi + P;

  // 0) split x, W into bf16 hi/lo planes
  split_inputs<<<(NX4 + NW4) / 256, 256, 0, stream>>>(x, W, xhi, xlo, Whi, Wlo);

  // 1) QKV projection (MFMA) -> Q/K/V planes
  gemm1_mfma<<<dim3(NQKV / 64, (Bc * Sc) / 128), 256, 0, stream>>>(
      xhi, xlo, Whi, Wlo, b, Qhi, Qlo, Khi, Klo, Vthi, Vtlo);

  // 2) MFMA flash attention -> Ot chunk planes
  attn_mfma<<<dim3(Sc / 64, Bc, Hc), 256, 0, stream>>>(
      Qhi, Qlo, Khi, Klo, Vthi, Vtlo, shift, mask, Othi, Otlo);

  // 3) output projection (MFMA) -> out
  gemm2_mfma<<<dim3(Dc / 64, (Bc * Sc) / 64), 256, 0, stream>>>(Othi, Otlo, Wo,
                                                               bo, out);
}

// Round 5
// 321.502 us; speedup vs baseline: 6.4776x; 1.0522x over previous
//
#include <hip/hip_runtime.h>
#include <math.h>

// Problem constants (fixed by reference)
constexpr int Bc = 2, Sc = 2048, Dc = 512, Hc = 8, DHc = 64;
constexpr int NQKV = 3 * Dc;  // 1536

typedef unsigned short u16;
typedef unsigned int u32;
typedef __attribute__((ext_vector_type(8))) __bf16 bf16x8;
typedef __attribute__((ext_vector_type(16))) float f32x16;

#define MFMA32 __builtin_amdgcn_mfma_f32_32x32x16_bf16

// Truncation hi/lo split of two floats, packed: ret.x = (hi(b)<<16)|hi(a),
// ret.y = lo-pair. hi = truncate-to-bf16; lo = bf16(residual).
__device__ inline uint2 splitpack2(float a, float b) {
  u32 ua = __float_as_uint(a), ub = __float_as_uint(b);
  u32 hi = (ub & 0xFFFF0000u) | (ua >> 16);
  float ra = a - __uint_as_float(ua & 0xFFFF0000u);
  float rb = b - __uint_as_float(ub & 0xFFFF0000u);
  u32 lo = (__float_as_uint(rb) & 0xFFFF0000u) | (__float_as_uint(ra) >> 16);
  return uint2{hi, lo};
}
__device__ inline void split1(float v, u16& hi, u16& lo) {
  u32 u = __float_as_uint(v);
  hi = (u16)(u >> 16);
  float r = v - __uint_as_float(u & 0xFFFF0000u);
  lo = (u16)(__float_as_uint(r) >> 16);
}

// ---------------------------------------------------------------------------
// Split x (4096x512) and W (1536x512) fp32 -> bf16 hi/lo planes (row-major).
// ---------------------------------------------------------------------------
constexpr int NX4 = (4096 * 512) / 4;  // 524288 float4s
constexpr int NW4 = (1536 * 512) / 4;  // 196608

__global__ __launch_bounds__(256) void split_inputs(
    const float* __restrict__ x, const float* __restrict__ W,
    u16* __restrict__ xhi, u16* __restrict__ xlo, u16* __restrict__ whi,
    u16* __restrict__ wlo) {
  const int f = blockIdx.x * 256 + threadIdx.x;
  const float* src;
  u16 *dh_, *dl_;
  int idx;
  if (f < NX4) {
    src = x; dh_ = xhi; dl_ = xlo; idx = f;
  } else {
    src = W; dh_ = whi; dl_ = wlo; idx = f - NX4;
  }
  const float4 v = ((const float4*)src)[idx];
  const uint2 p0 = splitpack2(v.x, v.y), p1 = splitpack2(v.z, v.w);
  ((uint2*)dh_)[idx] = uint2{p0.x, p1.x};
  ((uint2*)dl_)[idx] = uint2{p0.y, p1.y};
}

// ---------------------------------------------------------------------------
// GEMM1 (MFMA): qkv = x @ W^T + b. Tiles 128x64, BK=32, 4 waves (2x2), each
// wave 2 m-tiles of 32x32. LDS in fragment-major layout [p][mt][t][lane][8].
// Epilogue splits to Q/K [h][b][s][dh] and V^T [h][b][dh][s] bf16 planes.
// ---------------------------------------------------------------------------
__global__ __launch_bounds__(256, 2) void gemm1_mfma(
    const u16* __restrict__ xhi, const u16* __restrict__ xlo,
    const u16* __restrict__ whi, const u16* __restrict__ wlo,
    const float* __restrict__ bias, u16* __restrict__ Qhi,
    u16* __restrict__ Qlo, u16* __restrict__ Khi, u16* __restrict__ Klo,
    u16* __restrict__ Vthi, u16* __restrict__ Vtlo) {
  __shared__ __align__(16) u16 Af[2][4][2][64][8];  // 16 KB
  __shared__ __align__(16) u16 Bf[2][2][2][64][8];  // 8 KB
  const int tid = threadIdx.x;
  const int wave = tid >> 6, lane = tid & 63, l31 = lane & 31, lhi = lane >> 5;
  const int wm = wave >> 1, wn = wave & 1;
  const int m0 = blockIdx.y * 128, n0 = blockIdx.x * 64;

  f32x16 acc[2];
#pragma unroll
  for (int r = 0; r < 16; ++r) {
    acc[0][r] = 0.f;
    acc[1][r] = 0.f;
  }

  for (int k0 = 0; k0 < 512; k0 += 32) {
    // stage A: 1024 16B chunks (2 planes x 128 m x 4 kc)
#pragma unroll
    for (int i = 0; i < 4; ++i) {
      const int f = i * 256 + tid;
      const int p = f >> 9, rem = f & 511, m = rem >> 2, c = rem & 3;
      const u16* src = (p ? xlo : xhi) + (size_t)(m0 + m) * 512 + k0 + c * 8;
      *(uint4*)&Af[p][m >> 5][c >> 1][(c & 1) * 32 + (m & 31)][0] =
          *(const uint4*)src;
    }
    // stage B: 512 chunks
#pragma unroll
    for (int i = 0; i < 2; ++i) {
      const int f = i * 256 + tid;
      const int p = f >> 8, rem = f & 255, n = rem >> 2, c = rem & 3;
      const u16* src = (p ? wlo : whi) + (size_t)(n0 + n) * 512 + k0 + c * 8;
      *(uint4*)&Bf[p][n >> 5][c >> 1][(c & 1) * 32 + (n & 31)][0] =
          *(const uint4*)src;
    }
    __syncthreads();
#pragma unroll
    for (int t = 0; t < 2; ++t) {
      const bf16x8 bh = *(const bf16x8*)&Bf[0][wn][t][lane][0];
      const bf16x8 bl = *(const bf16x8*)&Bf[1][wn][t][lane][0];
#pragma unroll
      for (int ti = 0; ti < 2; ++ti) {
        const bf16x8 ah = *(const bf16x8*)&Af[0][wm * 2 + ti][t][lane][0];
        const bf16x8 al = *(const bf16x8*)&Af[1][wm * 2 + ti][t][lane][0];
        acc[ti] = MFMA32(ah, bh, acc[ti], 0, 0, 0);
        acc[ti] = MFMA32(ah, bl, acc[ti], 0, 0, 0);
        acc[ti] = MFMA32(al, bh, acc[ti], 0, 0, 0);
      }
    }
    __syncthreads();
  }

  // epilogue: C col (lane&31) = n, rows per reg. t3 uniform per wave.
  const int n = n0 + wn * 32 + l31;
  const float bn = bias[n];
  const int h = n / 192, rem = n - h * 192, t3 = rem >> 6, dh = rem & 63;
#pragma unroll
  for (int ti = 0; ti < 2; ++ti)
#pragma unroll
    for (int r = 0; r < 16; ++r) {
      const int m = m0 + wm * 64 + ti * 32 + (r & 3) + 8 * (r >> 2) + 4 * lhi;
      const int batch = m >> 11, s = m & 2047;
      const float val = acc[ti][r] + bn;
      u16 hi, lo;
      split1(val, hi, lo);
      const int hbq = h * 2 + batch;
      if (t3 == 2) {
        const size_t idx = ((size_t)hbq * 64 + dh) * 2048 + s;
        Vthi[idx] = hi;
        Vtlo[idx] = lo;
      } else {
        const size_t idx = ((size_t)hbq * 2048 + s) * 64 + dh;
        if (t3 == 0) {
          Qhi[idx] = hi;
          Qlo[idx] = lo;
        } else {
          Khi[idx] = hi;
          Klo[idx] = lo;
        }
      }
    }
}

// ---------------------------------------------------------------------------
// MFMA flash attention. Block = 4 waves = (wq 0..1) x (wk 0..1); 64 q/block.
// Key fix vs R4: shift/mask are staged cooperatively (coalesced float4 row
// reads) into per-wave fp32 LDS chunks as a = mask ? hs*shift : 1e9 sentinel.
// Each wave's Sa chunk is aliased with its private P region (Sa dead after
// logits; same-wave DS ordering makes the overlay safe; chunks wave-private).
// LDS pool 48 KB: Kf 16K | Vf 16K | SaP 16K. 2 barriers/iter.
// ---------------------------------------------------------------------------
__global__ __launch_bounds__(256, 2) void attn_mfma(
    const u16* __restrict__ Qhi, const u16* __restrict__ Qlo,
    const u16* __restrict__ Khi, const u16* __restrict__ Klo,
    const u16* __restrict__ Vthi, const u16* __restrict__ Vtlo,
    const float* __restrict__ shift, const float* __restrict__ mask,
    u16* __restrict__ Othi, u16* __restrict__ Otlo) {
  const int h = blockIdx.z, b = blockIdx.y;
  const int q0 = blockIdx.x * 64;
  const int tid = threadIdx.x;
  const int wave = tid >> 6;
  const int wq = wave >> 1, wk = wave & 1;
  const int lane = tid & 63;
  const int l31 = lane & 31, lhi = lane >> 5;

  // 48 KB pool: Kf [pl2][wk2][t4][64][8] @0 ; Vf [pl2][wk2][mt2][t2][64][8]
  // @8192 ; SaP 4x4KB per-wave chunks @16384 (fp32 Sa overlaid by u16 P).
  __shared__ __align__(16) u16 smem[24576];
  u16* Kf = smem;
  u16* Vf = smem + 8192;
  float* SaBase = (float*)(smem + 16384);      // 4 chunks x 1024 floats
  u16* Pw = smem + 16384 + wave * 2048;        // this wave's P chunk
  const float* SaW = SaBase + wave * 1024;     // this wave's Sa chunk

  const size_t hb = (size_t)h * Bc + b;
  const int qg = q0 + wq * 32 + l31;

  // Q B-frags from global: n=q (l31), k = t*16 + lhi*8 + j
  bf16x8 qf[2][4];
  {
    const size_t qbase = (hb * Sc + qg) * DHc;
#pragma unroll
    for (int t = 0; t < 4; ++t) {
      qf[0][t] = *(const bf16x8*)(Qhi + qbase + t * 16 + lhi * 8);
      qf[1][t] = *(const bf16x8*)(Qlo + qbase + t * 16 + lhi * 8);
    }
  }
  const float hs = exp2f(-(float)h);

  float m_run = -INFINITY, l_run = 0.f;
  f32x16 o0, o1;
#pragma unroll
  for (int i = 0; i < 16; ++i) {
    o0[i] = 0.f;
    o1[i] = 0.f;
  }

  // Sa staging map: thread -> (q = tid>>2, kc = tid&3), 16 keys per thread.
  const int sq = tid >> 2, skc = tid & 3;
  const float* srow0 = shift + ((size_t)b * Sc + q0 + sq) * Sc + skc * 16;
  const float* mrow0 = mask + ((size_t)b * Sc + q0 + sq) * Sc + skc * 16;
  float* SaSt = SaBase + ((sq >> 5) * 2 + (skc >> 1)) * 1024 + (sq & 31);
  const int skl2 = (skc & 1) * 16;  // key offset within the 32-key chunk

  for (int it = 0; it < 32; ++it) {
    const int kt = it * 64 + wk * 32;
    // ---- stage Sa (all threads): coalesced row-segment reads, fused mask
#pragma unroll
    for (int j = 0; j < 4; ++j) {
      const float4 s4 = *(const float4*)(srow0 + it * 64 + j * 4);
      const float4 m4 = *(const float4*)(mrow0 + it * 64 + j * 4);
      float* dst = SaSt + (skl2 + j * 4) * 32;
      dst[0] = (m4.x != 0.f) ? hs * s4.x : 1e9f;
      dst[32] = (m4.y != 0.f) ? hs * s4.y : 1e9f;
      dst[64] = (m4.z != 0.f) ? hs * s4.z : 1e9f;
      dst[96] = (m4.w != 0.f) ? hs * s4.w : 1e9f;
    }
    // ---- stage K (wq=0 waves) / V^T (wq=1 waves)
    if (wq == 0) {
      const int r = lane >> 1, half = lane & 1;
      const size_t gb = (hb * Sc + kt + r) * 64 + half * 32;
#pragma unroll
      for (int c = 0; c < 4; ++c) {
        const int dhc = half * 32 + c * 8;
        const int t = dhc >> 4, lh = (dhc >> 3) & 1;
        *(uint4*)&Kf[(((0 * 2 + wk) * 4 + t) * 64 + lh * 32 + r) * 8] =
            *(const uint4*)(Khi + gb + c * 8);
        *(uint4*)&Kf[(((1 * 2 + wk) * 4 + t) * 64 + lh * 32 + r) * 8] =
            *(const uint4*)(Klo + gb + c * 8);
      }
    } else {
      const size_t gb = (hb * 64 + lane) * 2048 + kt;  // lane = dh
      const int mt = lane >> 5, dl = lane & 31;
#pragma unroll
      for (int c = 0; c < 4; ++c) {
        const int t = c >> 1, lh = c & 1;
        *(uint4*)&Vf[((((0 * 2 + wk) * 2 + mt) * 2 + t) * 64 + lh * 32 + dl) * 8] =
            *(const uint4*)(Vthi + gb + c * 8);
        *(uint4*)&Vf[((((1 * 2 + wk) * 2 + mt) * 2 + t) * 64 + lh * 32 + dl) * 8] =
            *(const uint4*)(Vtlo + gb + c * 8);
      }
    }
    __syncthreads();

    // ---- S^T = K·Q^T (m=key, n=q): Khi*Qhi + Khi*Qlo + Klo*Qhi
    f32x16 s;
#pragma unroll
    for (int i = 0; i < 16; ++i) s[i] = 0.f;
#pragma unroll
    for (int t = 0; t < 4; ++t) {
      const bf16x8 kh = *(const bf16x8*)&Kf[(((0 * 2 + wk) * 4 + t) * 64 + lane) * 8];
      const bf16x8 kl = *(const bf16x8*)&Kf[(((1 * 2 + wk) * 4 + t) * 64 + lane) * 8];
      s = MFMA32(kh, qf[0][t], s, 0, 0, 0);
      s = MFMA32(kh, qf[1][t], s, 0, 0, 0);
      s = MFMA32(kl, qf[0][t], s, 0, 0, 0);
    }

    // ---- logits from LDS Sa (own chunk; key = 8c+4lhi+e local, q = l31)
    float p[16];
    float kmax = -INFINITY;
#pragma unroll
    for (int c = 0; c < 4; ++c) {
#pragma unroll
      for (int e = 0; e < 4; ++e) {
        const float a = SaW[(c * 8 + lhi * 4 + e) * 32 + l31];
        const float lg = s[4 * c + e] * 0.125f - a;
        p[4 * c + e] = lg;
        kmax = fmaxf(kmax, lg);
      }
    }
    kmax = fmaxf(kmax, __shfl_xor(kmax, 32, 64));
    const float mnew = fmaxf(m_run, kmax);
    const float alpha = __expf(m_run - mnew);
    float rsum = 0.f;
#pragma unroll
    for (int r = 0; r < 16; ++r) {
      p[r] = __expf(p[r] - mnew);
      rsum += p[r];
    }
    rsum += __shfl_xor(rsum, 32, 64);
    l_run = l_run * alpha + rsum;
    m_run = mnew;
#pragma unroll
    for (int i = 0; i < 16; ++i) {
      o0[i] *= alpha;
      o1[i] *= alpha;
    }

    // ---- P -> own chunk (overlays Sa, dead now). Frag layout as R4.
#pragma unroll
    for (int c = 0; c < 4; ++c) {
      const uint2 s01 = splitpack2(p[4 * c + 0], p[4 * c + 1]);
      const uint2 s23 = splitpack2(p[4 * c + 2], p[4 * c + 3]);
      const int t = c >> 1, lh = c & 1;
      const int bi = (t * 64 + lh * 32 + l31) * 8 + lhi * 4;
      *(uint2*)&Pw[bi] = uint2{s01.x, s23.x};
      *(uint2*)&Pw[1024 + bi] = uint2{s01.y, s23.y};
    }

    // ---- O^T += V^T · P^T
#pragma unroll
    for (int t = 0; t < 2; ++t) {
      const bf16x8 ph = *(const bf16x8*)&Pw[(t * 64 + lane) * 8];
      const bf16x8 pl_ = *(const bf16x8*)&Pw[1024 + (t * 64 + lane) * 8];
      bf16x8 vh = *(const bf16x8*)&Vf[((((0 * 2 + wk) * 2 + 0) * 2 + t) * 64 + lane) * 8];
      bf16x8 vl = *(const bf16x8*)&Vf[((((1 * 2 + wk) * 2 + 0) * 2 + t) * 64 + lane) * 8];
      o0 = MFMA32(vh, ph, o0, 0, 0, 0);
      o0 = MFMA32(vh, pl_, o0, 0, 0, 0);
      o0 = MFMA32(vl, ph, o0, 0, 0, 0);
      vh = *(const bf16x8*)&Vf[((((0 * 2 + wk) * 2 + 1) * 2 + t) * 64 + lane) * 8];
      vl = *(const bf16x8*)&Vf[((((1 * 2 + wk) * 2 + 1) * 2 + t) * 64 + lane) * 8];
      o1 = MFMA32(vh, ph, o1, 0, 0, 0);
      o1 = MFMA32(vh, pl_, o1, 0, 0, 0);
      o1 = MFMA32(vl, ph, o1, 0, 0, 0);
    }
    __syncthreads();
  }

  // ---- merge wk=0/1 (same wq) through LDS (aliases K/V pool; post-barrier)
  float* mL = (float*)smem;  // [64]
  float* lL = mL + 64;       // [64]
  float* Om = lL + 64;       // [2][64][33]
  if (wk == 1) {
    if (lhi == 0) {
      mL[wq * 32 + l31] = m_run;
      lL[wq * 32 + l31] = l_run;
    }
#pragma unroll
    for (int mt = 0; mt < 2; ++mt)
#pragma unroll
      for (int r = 0; r < 16; ++r) {
        const int row = mt * 32 + (r & 3) + 8 * (r >> 2) + 4 * lhi;
        Om[(wq * 64 + row) * 33 + l31] = (mt ? o1[r] : o0[r]);
      }
  }
  __syncthreads();
  if (wk == 0) {
    const float m1 = mL[wq * 32 + l31];
    const float l1v = lL[wq * 32 + l31];
    const float mst = fmaxf(m_run, m1);
    const float a0 = __expf(m_run - mst), a1 = __expf(m1 - mst);
    const float inv = 1.f / (a0 * l_run + a1 * l1v);
    const int tok = b * 2048 + qg;
#pragma unroll
    for (int mt = 0; mt < 2; ++mt)
#pragma unroll
      for (int r = 0; r < 16; ++r) {
        const int row = mt * 32 + (r & 3) + 8 * (r >> 2) + 4 * lhi;
        const float val =
            (a0 * (mt ? o1[r] : o0[r]) + a1 * Om[(wq * 64 + row) * 33 + l31]) *
            inv;
        const int d = h * 64 + row;
        u16 hi, lo;
        split1(val, hi, lo);
        const size_t idx = ((size_t)(d >> 3) * 4096 + tok) * 8 + (d & 7);
        Othi[idx] = hi;
        Otlo[idx] = lo;
      }
  }
}

// ---------------------------------------------------------------------------
// GEMM2 (MFMA): out = o @ Wo^T + bo. A from Otc chunk planes (b128 staging),
// B = Wo fp32 converted inline. Tiles 64x64, BK=32, 4 waves (2x2), 1 tile ea.
// ---------------------------------------------------------------------------
__global__ __launch_bounds__(256, 2) void gemm2_mfma(
    const u16* __restrict__ Othi, const u16* __restrict__ Otlo,
    const float* __restrict__ Wo, const float* __restrict__ bo,
    float* __restrict__ out) {
  __shared__ __align__(16) u16 Af[2][2][2][64][8];  // 8 KB
  __shared__ __align__(16) u16 Bf[2][2][2][64][8];  // 8 KB
  const int tid = threadIdx.x;
  const int wave = tid >> 6, lane = tid & 63, l31 = lane & 31, lhi = lane >> 5;
  const int wm = wave >> 1, wn = wave & 1;
  const int m0 = blockIdx.y * 64, n0 = blockIdx.x * 64;

  f32x16 acc;
#pragma unroll
  for (int r = 0; r < 16; ++r) acc[r] = 0.f;

  for (int k0 = 0; k0 < 512; k0 += 32) {
    // A: 512 chunks from Otc layout ((kglob>>3)*4096 + token)*8 + (kglob&7)
#pragma unroll
    for (int i = 0; i < 2; ++i) {
      const int f = i * 256 + tid;
      const int p = f >> 8, rem = f & 255, c = rem >> 6, tok = rem & 63;
      const u16* src =
          (p ? Otlo : Othi) + ((size_t)(k0 / 8 + c) * 4096 + m0 + tok) * 8;
      *(uint4*)&Af[p][tok >> 5][c >> 1][(c & 1) * 32 + (tok & 31)][0] =
          *(const uint4*)src;
    }
    // B: Wo fp32 rows, inline truncation split
    {
      const int n = tid >> 2, c = tid & 3;
      const float* src = Wo + (size_t)(n0 + n) * 512 + k0 + c * 8;
      const float4 v0 = *(const float4*)src;
      const float4 v1 = *(const float4*)(src + 4);
      const uint2 q0 = splitpack2(v0.x, v0.y), q1 = splitpack2(v0.z, v0.w);
      const uint2 q2 = splitpack2(v1.x, v1.y), q3 = splitpack2(v1.z, v1.w);
      const uint4 hi4 = {q0.x, q1.x, q2.x, q3.x};
      const uint4 lo4 = {q0.y, q1.y, q2.y, q3.y};
      *(uint4*)&Bf[0][n >> 5][c >> 1][(c & 1) * 32 + (n & 31)][0] = hi4;
      *(uint4*)&Bf[1][n >> 5][c >> 1][(c & 1) * 32 + (n & 31)][0] = lo4;
    }
    __syncthreads();
#pragma unroll
    for (int t = 0; t < 2; ++t) {
      const bf16x8 ah = *(const bf16x8*)&Af[0][wm][t][lane][0];
      const bf16x8 al = *(const bf16x8*)&Af[1][wm][t][lane][0];
      const bf16x8 bh = *(const bf16x8*)&Bf[0][wn][t][lane][0];
      const bf16x8 bl = *(const bf16x8*)&Bf[1][wn][t][lane][0];
      acc = MFMA32(ah, bh, acc, 0, 0, 0);
      acc = MFMA32(ah, bl, acc, 0, 0, 0);
      acc = MFMA32(al, bh, acc, 0, 0, 0);
    }
    __syncthreads();
  }

  const int n = n0 + wn * 32 + l31;
  const float bn = bo[n];
#pragma unroll
  for (int r = 0; r < 16; ++r) {
    const int m = m0 + wm * 32 + (r & 3) + 8 * (r >> 2) + 4 * lhi;
    out[(size_t)m * 512 + n] = acc[r] + bn;
  }
}

// ---------------------------------------------------------------------------
extern "C" void kernel_launch(void* const* d_in, const int* in_sizes, int n_in,
                              void* d_out, int out_size, void* d_ws,
                              size_t ws_size, hipStream_t stream) {
  const float* x = (const float*)d_in[0];
  const float* shift = (const float*)d_in[1];
  const float* mask = (const float*)d_in[2];
  const float* W = (const float*)d_in[3];
  const float* b = (const float*)d_in[4];
  const float* Wo = (const float*)d_in[5];
  const float* bo = (const float*)d_in[6];
  float* out = (float*)d_out;

  // ws (32 MiB): [0,6P): Q/K/V hi+lo planes. [6P,8P): phase-1 W planes,
  // later overwritten by Ot planes (W dead after gemm1).
  // d_out (8 MiB) doubles as x hi/lo planes until gemm2 writes the output.
  const size_t P = (size_t)Hc * Bc * Sc * DHc;  // 2,097,152
  u16* ws0 = (u16*)d_ws;
  u16* Qhi = ws0;
  u16* Qlo = ws0 + P;
  u16* Khi = ws0 + 2 * P;
  u16* Klo = ws0 + 3 * P;
  u16* Vthi = ws0 + 4 * P;
  u16* Vtlo = ws0 + 5 * P;
  u16* Whi = ws0 + 6 * P;
  u16* Wlo = Whi + (size_t)NQKV * Dc;  // 786,432 elements
  u16* Othi = ws0 + 6 * P;             // aliases dead W planes
  u16* Otlo = ws0 + 7 * P;
  u16* xhi = (u16*)d_out;
  u16* xlo = xhi + P;

  // 0) split x, W into bf16 hi/lo planes
  split_inputs<<<(NX4 + NW4) / 256, 256, 0, stream>>>(x, W, xhi, xlo, Whi, Wlo);

  // 1) QKV projection (MFMA) -> Q/K/V planes
  gemm1_mfma<<<dim3(NQKV / 64, (Bc * Sc) / 128), 256, 0, stream>>>(
      xhi, xlo, Whi, Wlo, b, Qhi, Qlo, Khi, Klo, Vthi, Vtlo);

  // 2) MFMA flash attention -> Ot chunk planes
  attn_mfma<<<dim3(Sc / 64, Bc, Hc), 256, 0, stream>>>(
      Qhi, Qlo, Khi, Klo, Vthi, Vtlo, shift, mask, Othi, Otlo);

  // 3) output projection (MFMA) -> out
  gemm2_mfma<<<dim3(Dc / 64, (Bc * Sc) / 64), 256, 0, stream>>>(Othi, Otlo, Wo,
                                                               bo, out);
}